// Round 16
// baseline (775.999 us; speedup 1.0000x reference)
//
#include <hip/hip_runtime.h>

#define L_DIM 128
#define BB 8          // real batch rows per block (padded to 16 for MFMA)

typedef _Float16 f16;
typedef _Float16 f16x4 __attribute__((ext_vector_type(4)));
typedef _Float16 f16x8 __attribute__((ext_vector_type(8)));
typedef float f32x4 __attribute__((ext_vector_type(4)));

// tanh(u + b) with bias pre-scaled into the exp2 argument: bk = 2*log2(e)*b.
__device__ __forceinline__ float fast_tanh_b(float x, float bk) {
    float e = __builtin_amdgcn_exp2f(fmaf(x, 2.8853900817779268f, bk));
    float r = __builtin_amdgcn_rcpf(e + 1.0f);
    return fmaf(-2.0f, r, 1.0f);   // large +x -> 1; large -x -> -1
}

// Spin on a monotone LDS counter. Volatile read -> reload each iteration; the
// spinning wave mostly waits on lgkmcnt, leaving issue slots to the sibling wave.
__device__ __forceinline__ void spin_ge(volatile int* f, int tgt) {
    while (*f < tgt) {}
    asm volatile("" ::: "memory");   // fence: no later LDS read moves above
}

// waves_per_eu(2): unified budget 256 regs/wave (128 arch + 128 AGPR w2f).
__attribute__((amdgpu_flat_work_group_size(512, 512), amdgpu_waves_per_eu(2)))
__global__ void
cde_kernel(const float* __restrict__ coeffs,
           const float* __restrict__ W_init, const float* __restrict__ b_init,
           const float* __restrict__ W1, const float* __restrict__ b1,
           const float* __restrict__ W2, const float* __restrict__ b2,
           const float* __restrict__ W_out, const float* __restrict__ b_out,
           float* __restrict__ out)
{
    // Double-buffered z (parity of eval e) + per-GROUP double-buffered h:
    // the two 4-wave groups sync only through z (soft flag), so their
    // MFMA-burst / VALU-tail phases can slide against each other.
    __shared__ __align__(16) f16   z16[2][16][72];        // rows 8-15 = 0 always
    __shared__ __align__(16) f16   h16g[2][2][16][136];   // [group][buf][b][hcol]
    __shared__ __align__(16) float zf[BB][64];            // epilogue gather
    __shared__ __align__(16) float dxb[128][16][8];       // deriv at integer t (+plane 127 = fr=1)
    __shared__ __align__(16) float dxm[127][16][8];       // deriv at t+0.5
    __shared__ int sflags[4];   // [0]=zw (8 adds/eval), [1]=hd g0, [2]=hd g1

    const int tid  = threadIdx.x;
    const int blk  = blockIdx.x;
    const int lane = tid & 63;
    const int w    = tid >> 6;        // wave 0..7
    const int q    = lane >> 4;       // quarter-wave 0..3
    const int lr   = lane & 15;
    const int g    = w >> 2;          // group 0: hh<32, group 1: hh>=32
    const int v    = w & 3;           // wave-in-group
    // GEMM2 column permutation (identical to r13): hh = w*8+(lr&7), c = 2*tau+(lr>>3)
    const int hh   = w * 8 + (lr & 7);
    const int chp  = lr >> 3;
    const int row0 = (q & 1) * 4 + (q >> 1) * 2;   // q: 0->0, 1->4, 2->2, 3->6

    // ---- one-time: weight fragments into registers ----
    f16x8 w2f[8][4];
    float b2k[8];
#pragma unroll
    for (int t8 = 0; t8 < 8; ++t8) {
        const int outc = hh * 16 + 2 * t8 + chp;
        b2k[t8] = 2.8853900817779268f * b2[outc];
#pragma unroll
        for (int kc = 0; kc < 4; ++kc) {
            const float* src = W2 + (size_t)outc * 128 + kc * 32 + q * 8;
            f16x8 vv;
#pragma unroll
            for (int i = 0; i < 8; ++i) vv[i] = (f16)src[i];
            w2f[t8][kc] = vv;
        }
    }
    // Redundant-G1 fragments: wave v covers hcols [v*32, v*32+32) = tiles 2v, 2v+1.
    f16x8 w1f[2][2];
#pragma unroll
    for (int n = 0; n < 2; ++n)
#pragma unroll
        for (int kc = 0; kc < 2; ++kc) {
            const float* src = W1 + (size_t)(v * 32 + n * 16 + lr) * 64 + kc * 32 + q * 8;
            f16x8 vv;
#pragma unroll
            for (int i = 0; i < 8; ++i) vv[i] = (f16)src[i];
            w1f[n][kc] = vv;
        }
    const float4 b1q0 = *(const float4*)&b1[v * 32 + q * 4];
    const float4 b1q1 = *(const float4*)&b1[v * 32 + 16 + q * 4];
    const f32x4 zero4 = {0.f, 0.f, 0.f, 0.f};

    // ---- init: z0 = X0 @ W_init^T + b_init for (b = row0+j, hh) ----
    float z32r[2], ksumr[2];
#pragma unroll
    for (int j = 0; j < 2; ++j) {
        const float* x0 = coeffs + (size_t)(blk * BB + row0 + j) * (L_DIM - 1) * 64;
        float a = b_init[hh];
#pragma unroll
        for (int c = 0; c < 16; ++c) a = fmaf(x0[c], W_init[hh * 16 + c], a);
        z32r[j] = a;
        ksumr[j] = 0.f;
        if (lr < 8) z16[0][row0 + j][hh] = (f16)a;   // lr<8 <=> chp==0; hh=w*8+lr
    }
    for (int i = tid; i < 2 * 8 * 72; i += 512)      // zero pad rows, BOTH buffers
        z16[i / (8 * 72)][8 + (i % (8 * 72)) / 72][i % 72] = (f16)0.f;
    if (tid == 0) { sflags[0] = 0; sflags[1] = 0; sflags[2] = 0; }

    // ---- prologue: whole-trajectory spline-deriv tables ----
#pragma unroll 2
    for (int i = tid; i < 127 * 128; i += 512) {
        const int t = i >> 7, j = i & 127;
        const int c = j & 15, b = (j >> 4) & 7;
        const float* seg = coeffs + ((size_t)(blk * BB + b) * (L_DIM - 1) + t) * 64;
        const float bv = seg[16 + c], cv = seg[32 + c], dv = seg[48 + c];
        dxb[t][c][b] = bv;
        dxm[t][c][b] = fmaf(0.25f, dv, fmaf(0.5f, cv, bv));
        if (t == 126) dxb[127][c][b] = bv + cv + dv;   // fr = 1 endpoint
    }
    __syncthreads();   // z(0), tables, flags all visible; the ONLY hard barrier

    // prime: group 1 starts one G1-phase behind group 0 (seed the anti-phase)
    if (g == 1) spin_ge(&sflags[1], 4);

#define G2T(dst, T) \
    f32x4 dst = __builtin_amdgcn_mfma_f32_16x16x32_f16(af0, w2f[T][0], zero4, 0, 0, 0); \
    dst = __builtin_amdgcn_mfma_f32_16x16x32_f16(af1, w2f[T][1], dst, 0, 0, 0);         \
    dst = __builtin_amdgcn_mfma_f32_16x16x32_f16(af2, w2f[T][2], dst, 0, 0, 0);         \
    dst = __builtin_amdgcn_mfma_f32_16x16x32_f16(af3, w2f[T][3], dst, 0, 0, 0);
#define G2TAIL(src, T) {                                                  \
    float u0 = __shfl_xor(src[2], 32);                                    \
    float u1 = __shfl_xor(src[3], 32);                                    \
    float g0 = fast_tanh_b((lane < 32) ? src[0] : u0, b2k[T]);            \
    float g1 = fast_tanh_b((lane < 32) ? src[1] : u1, b2k[T]);            \
    ka0 = fmaf(g0, dvv[(T) & 3].x, ka0);                                  \
    ka1 = fmaf(g1, dvv[(T) & 3].y, ka1); }

    // ---- main loop: 508 evals, NO barriers — soft flag sync only ----
    for (int t = 0; t < L_DIM - 1; ++t) {
#pragma unroll
        for (int s = 0; s < 4; ++s) {
            const int e  = 4 * t + s;
            const int eb = e & 1;
            spin_ge(&sflags[0], 8 * e);            // z(e) fully written

            // Phase A: redundant G1 (this group computes FULL h into its private buf)
            {
                const f16x8 zb0 = *(const f16x8*)&z16[eb][lr][q * 8];
                const f16x8 zb1 = *(const f16x8*)&z16[eb][lr][32 + q * 8];
#pragma unroll
                for (int n = 0; n < 2; ++n) {
                    f32x4 hacc = __builtin_amdgcn_mfma_f32_16x16x32_f16(w1f[n][0], zb0, zero4, 0, 0, 0);
                    hacc = __builtin_amdgcn_mfma_f32_16x16x32_f16(w1f[n][1], zb1, hacc, 0, 0, 0);
                    const float4 bq = n ? b1q1 : b1q0;
                    f16x4 pp;
                    pp[0] = (f16)fmaxf(hacc[0] + bq.x, 0.f);
                    pp[1] = (f16)fmaxf(hacc[1] + bq.y, 0.f);
                    pp[2] = (f16)fmaxf(hacc[2] + bq.z, 0.f);
                    pp[3] = (f16)fmaxf(hacc[3] + bq.w, 0.f);
                    *(f16x4*)&h16g[g][eb][lr][(2 * v + n) * 16 + q * 4] = pp;
                }
            }
            asm volatile("s_waitcnt lgkmcnt(0)" ::: "memory");
            if (lane == 0) atomicAdd((int*)&sflags[1 + g], 1);
            spin_ge(&sflags[1 + g], 4 * (e + 1));  // group's h(e) complete

            // Phase B: GEMM2 (r13 2-pass tile-interleave) from PRIVATE h buffer
            const float* dxp = (s == 0) ? &dxb[t][0][0]
                             : (s == 3) ? &dxb[t + 1][0][0]
                                        : &dxm[t][0][0];
            const f16x8 af0 = *(const f16x8*)&h16g[g][eb][lr][q * 8];
            const f16x8 af1 = *(const f16x8*)&h16g[g][eb][lr][32 + q * 8];
            const f16x8 af2 = *(const f16x8*)&h16g[g][eb][lr][64 + q * 8];
            const f16x8 af3 = *(const f16x8*)&h16g[g][eb][lr][96 + q * 8];
            float ka0 = 0.f, ka1 = 0.f;
#pragma unroll
            for (int hf = 0; hf < 2; ++hf) {
                float2 dvv[4];
#pragma unroll
                for (int tt = 0; tt < 4; ++tt)
                    dvv[tt] = *(const float2*)&dxp[(2 * (hf * 4 + tt) + chp) * 8 + row0];
                G2T(a0, hf * 4 + 0)
                G2T(a1, hf * 4 + 1)
                G2TAIL(a0, hf * 4 + 0)              // overlaps a1's drain
                G2T(a2, hf * 4 + 2)
                G2TAIL(a1, hf * 4 + 1)
                G2T(a3, hf * 4 + 3)
                G2TAIL(a2, hf * 4 + 2)
                G2TAIL(a3, hf * 4 + 3)
            }
            ka0 += __shfl_xor(ka0, 8);
            ka1 += __shfl_xor(ka1, 8);
            // RK4 stage update in registers
            float zs0, zs1;
            if (s == 3) {
                z32r[0] = fmaf(ksumr[0] + ka0, 1.f / 6.f, z32r[0]); zs0 = z32r[0];
                z32r[1] = fmaf(ksumr[1] + ka1, 1.f / 6.f, z32r[1]); zs1 = z32r[1];
            } else {
                ksumr[0] = (s == 0) ? ka0 : fmaf(2.f, ka0, ksumr[0]);
                ksumr[1] = (s == 0) ? ka1 : fmaf(2.f, ka1, ksumr[1]);
                const float alpha = (s == 2) ? 1.f : 0.5f;
                zs0 = fmaf(alpha, ka0, z32r[0]);
                zs1 = fmaf(alpha, ka1, z32r[1]);
            }
            if (lr < 8) {
                z16[eb ^ 1][row0 + 0][hh] = (f16)zs0;
                z16[eb ^ 1][row0 + 1][hh] = (f16)zs1;
            }
            asm volatile("s_waitcnt lgkmcnt(0)" ::: "memory");
            if (lane == 0) atomicAdd((int*)&sflags[0], 1);
        }
    }

    // ---- epilogue: out = zT @ W_out^T + b_out ----
    __syncthreads();
    if (lr < 8) {
        zf[row0 + 0][hh] = z32r[0];
        zf[row0 + 1][hh] = z32r[1];
    }
    __syncthreads();
    if (tid < 64) {
        const int b = lane >> 3, j0 = lane & 7;
        float p = 0.f;
#pragma unroll
        for (int m = 0; m < 8; ++m) p += zf[b][j0 + 8 * m] * W_out[j0 + 8 * m];
        p += __shfl_xor(p, 1, 64);
        p += __shfl_xor(p, 2, 64);
        p += __shfl_xor(p, 4, 64);
        if (j0 == 0) out[blk * BB + b] = p + b_out[0];
    }
}

extern "C" void kernel_launch(void* const* d_in, const int* in_sizes, int n_in,
                              void* d_out, int out_size, void* d_ws, size_t ws_size,
                              hipStream_t stream) {
    const float* coeffs = (const float*)d_in[0];
    const float* W_init = (const float*)d_in[1];
    const float* b_init = (const float*)d_in[2];
    const float* W1     = (const float*)d_in[3];
    const float* b1     = (const float*)d_in[4];
    const float* W2     = (const float*)d_in[5];
    const float* b2     = (const float*)d_in[6];
    const float* W_out  = (const float*)d_in[7];
    const float* b_out  = (const float*)d_in[8];
    cde_kernel<<<256, 512, 0, stream>>>(coeffs, W_init, b_init, W1, b1, W2, b2,
                                        W_out, b_out, (float*)d_out);
}

// Round 17
// 693.713 us; speedup vs baseline: 1.1186x; 1.1186x over previous
//
#include <hip/hip_runtime.h>

#define L_DIM 128
#define BB 8          // real batch rows per block (padded to 16 for MFMA)

typedef _Float16 f16;
typedef _Float16 f16x4 __attribute__((ext_vector_type(4)));
typedef _Float16 f16x8 __attribute__((ext_vector_type(8)));
typedef float f32x4 __attribute__((ext_vector_type(4)));

// tanh(u + b) with bias pre-scaled into the exp2 argument: bk = 2*log2(e)*b.
__device__ __forceinline__ float fast_tanh_b(float x, float bk) {
    float e = __builtin_amdgcn_exp2f(fmaf(x, 2.8853900817779268f, bk));
    float r = __builtin_amdgcn_rcpf(e + 1.0f);
    return fmaf(-2.0f, r, 1.0f);   // large +x -> 1; large -x -> -1
}

// waves_per_eu(2): unified budget 256 regs/wave (128 arch + 128 AGPR w2f).
__attribute__((amdgpu_flat_work_group_size(512, 512), amdgpu_waves_per_eu(2)))
__global__ void
cde_kernel(const float* __restrict__ coeffs,
           const float* __restrict__ W_init, const float* __restrict__ b_init,
           const float* __restrict__ W1, const float* __restrict__ b1,
           const float* __restrict__ W2, const float* __restrict__ b2,
           const float* __restrict__ W_out, const float* __restrict__ b_out,
           float* __restrict__ out)
{
    __shared__ __align__(16) f16   z16[16][72];     // fp16 z (rows 8-15 = 0, static)
    __shared__ __align__(16) f16   h16[16][136];    // fp16 hidden activations
    __shared__ __align__(16) float zf[BB][64];      // epilogue gather
    // Whole-trajectory spline-deriv tables (read-only after prologue ->
    // dvv loads are hoistable across barriers with no race).
    __shared__ __align__(16) float dxb[128][16][8];  // 64KB (plane 127 = fr=1 endpoint)
    __shared__ __align__(16) float dxm[127][16][8];  // 63.5KB

    const int tid  = threadIdx.x;
    const int blk  = blockIdx.x;
    const int lane = tid & 63;
    const int w    = tid >> 6;        // wave 0..7
    const int q    = lane >> 4;       // quarter-wave 0..3
    const int lr   = lane & 15;
    // GEMM2 column permutation: col lr of tile tau -> outc = hh*16 + c with
    //   hh = w*8 + (lr&7)  (lane-invariant over tau),  c = 2*tau + (lr>>3)
    // => c-sum = register accumulate over tau + ONE shfl_xor(8) per hf-half.
    const int hh   = w * 8 + (lr & 7);
    const int chp  = lr >> 3;
    // After lane-compression this lane owns rows row0, row0+1 (all real):
    const int row0 = (q & 1) * 4 + (q >> 1) * 2;   // q: 0->0, 1->4, 2->2, 3->6

    // ---- one-time: weight fragments into registers ----
    f16x8 w2f[8][4];
    float b2k[8];
#pragma unroll
    for (int t8 = 0; t8 < 8; ++t8) {
        const int outc = hh * 16 + 2 * t8 + chp;
        b2k[t8] = 2.8853900817779268f * b2[outc];
#pragma unroll
        for (int kc = 0; kc < 4; ++kc) {
            const float* src = W2 + (size_t)outc * 128 + kc * 32 + q * 8;
            f16x8 v;
#pragma unroll
            for (int i = 0; i < 8; ++i) v[i] = (f16)src[i];
            w2f[t8][kc] = v;
        }
    }
    f16x8 w1f[2];
#pragma unroll
    for (int kc = 0; kc < 2; ++kc) {
        const float* src = W1 + (size_t)(w * 16 + lr) * 64 + kc * 32 + q * 8;
        f16x8 v;
#pragma unroll
        for (int i = 0; i < 8; ++i) v[i] = (f16)src[i];
        w1f[kc] = v;
    }
    // Swapped-G1 bias quad: lane owns hcols w*16 + q*4 + 0..3
    const float4 b1q = *(const float4*)&b1[w * 16 + q * 4];
    const f32x4 zero4 = {0.f, 0.f, 0.f, 0.f};

    // ---- init: z0 = X0 @ W_init^T + b_init for (b = row0+j, hh) ----
    float z32r[2], ksumr[2];
#pragma unroll
    for (int j = 0; j < 2; ++j) {
        const float* x0 = coeffs + (size_t)(blk * BB + row0 + j) * (L_DIM - 1) * 64;
        float a = b_init[hh];
#pragma unroll
        for (int c = 0; c < 16; ++c) a = fmaf(x0[c], W_init[hh * 16 + c], a);
        z32r[j] = a;
        ksumr[j] = 0.f;
        if (lr < 8) z16[row0 + j][hh] = (f16)a;   // lr<8 <=> chp==0; hh=w*8+lr
    }
    for (int i = tid; i < 8 * 72; i += 512) z16[8 + i / 72][i % 72] = (f16)0.f;  // pad rows

    // ---- prologue: fill the whole dx table (c-fast mapping for coalescing) ----
#pragma unroll 2
    for (int i = tid; i < 127 * 128; i += 512) {
        const int t = i >> 7, j = i & 127;
        const int c = j & 15, b = (j >> 4) & 7;
        const float* seg = coeffs + ((size_t)(blk * BB + b) * (L_DIM - 1) + t) * 64;
        const float bv = seg[16 + c], cv = seg[32 + c], dv = seg[48 + c];
        dxb[t][c][b] = bv;
        dxm[t][c][b] = fmaf(0.25f, dv, fmaf(0.5f, cv, bv));
        if (t == 126) dxb[127][c][b] = bv + cv + dv;   // fr = 1 endpoint
    }
    __syncthreads();

    // 4-MFMA chain for one tile (C from persistent zero quad)
#define G2T(dst, T) \
    f32x4 dst = __builtin_amdgcn_mfma_f32_16x16x32_f16(af0, w2f[T][0], zero4, 0, 0, 0); \
    dst = __builtin_amdgcn_mfma_f32_16x16x32_f16(af1, w2f[T][1], dst, 0, 0, 0);         \
    dst = __builtin_amdgcn_mfma_f32_16x16x32_f16(af2, w2f[T][2], dst, 0, 0, 0);         \
    dst = __builtin_amdgcn_mfma_f32_16x16x32_f16(af3, w2f[T][3], dst, 0, 0, 0);
    // tail: compress (rows 0-7 real) -> tanh -> dX-fma into the given accumulators
#define G2TAILX(src, T, DV, K0, K1) {                                     \
    float u0 = __shfl_xor(src[2], 32);                                    \
    float u1 = __shfl_xor(src[3], 32);                                    \
    float g0 = fast_tanh_b((lane < 32) ? src[0] : u0, b2k[T]);            \
    float g1 = fast_tanh_b((lane < 32) ? src[1] : u1, b2k[T]);            \
    K0 = fmaf(g0, DV[(T) & 3].x, K0);                                     \
    K1 = fmaf(g1, DV[(T) & 3].y, K1); }

    // ---- main loop: 127 RK4 steps x 4 f-evals, 2 barriers per f-eval ----
    for (int t = 0; t < L_DIM - 1; ++t) {
#pragma unroll
        for (int s = 0; s < 4; ++s) {
            // dX plane for this stage; hf0's four dvv loads HOISTED above the
            // barrier (tables are read-only) -> latency hides under G1+barrier.
            const float* dxp = (s == 0) ? &dxb[t][0][0]
                             : (s == 3) ? &dxb[t + 1][0][0]
                                        : &dxm[t][0][0];
            float2 dvvA[4];
#pragma unroll
            for (int tt = 0; tt < 4; ++tt)
                dvvA[tt] = *(const float2*)&dxp[(2 * tt + chp) * 8 + row0];

            // Phase A: GEMM1, swapped operands: D[hcol][batch]. Lane holds 4
            // CONSECUTIVE hcols (w*16+q*4+r) for batch lr -> one b64 write.
            {
                f16x8 za0 = *(const f16x8*)&z16[lr][q * 8];
                f16x8 za1 = *(const f16x8*)&z16[lr][32 + q * 8];
                f32x4 hacc = __builtin_amdgcn_mfma_f32_16x16x32_f16(w1f[0], za0, zero4, 0, 0, 0);
                hacc = __builtin_amdgcn_mfma_f32_16x16x32_f16(w1f[1], za1, hacc, 0, 0, 0);
                f16x4 pp;
                pp[0] = (f16)fmaxf(hacc[0] + b1q.x, 0.f);
                pp[1] = (f16)fmaxf(hacc[1] + b1q.y, 0.f);
                pp[2] = (f16)fmaxf(hacc[2] + b1q.z, 0.f);
                pp[3] = (f16)fmaxf(hacc[3] + b1q.w, 0.f);
                *(f16x4*)&h16[lr][w * 16 + q * 4] = pp;
            }
            __syncthreads();

            // Phase B: GEMM2, 2-pass tile-interleave (r13). hf0's partial c-sum
            // shuffle issues DURING hf1's first MFMA drain; only hf1's shuffle
            // stays exposed at the end.
            const f16x8 af0 = *(const f16x8*)&h16[lr][q * 8];
            const f16x8 af1 = *(const f16x8*)&h16[lr][32 + q * 8];
            const f16x8 af2 = *(const f16x8*)&h16[lr][64 + q * 8];
            const f16x8 af3 = *(const f16x8*)&h16[lr][96 + q * 8];
            float ra0 = 0.f, ra1 = 0.f, rb0 = 0.f, rb1 = 0.f;
            G2T(a0, 0)
            G2T(a1, 1)
            float2 dvvB[4];
#pragma unroll
            for (int tt = 0; tt < 4; ++tt)
                dvvB[tt] = *(const float2*)&dxp[(2 * (4 + tt) + chp) * 8 + row0];
            G2TAILX(a0, 0, dvvA, ra0, ra1)
            G2T(a2, 2)
            G2TAILX(a1, 1, dvvA, ra0, ra1)
            G2T(a3, 3)
            G2TAILX(a2, 2, dvvA, ra0, ra1)
            G2TAILX(a3, 3, dvvA, ra0, ra1)
            G2T(a4, 4)
            G2T(a5, 5)
            const float sa0 = __shfl_xor(ra0, 8);   // hidden under a4/a5 drain
            const float sa1 = __shfl_xor(ra1, 8);
            G2TAILX(a4, 4, dvvB, rb0, rb1)
            G2T(a6, 6)
            G2TAILX(a5, 5, dvvB, rb0, rb1)
            G2T(a7, 7)
            G2TAILX(a6, 6, dvvB, rb0, rb1)
            G2TAILX(a7, 7, dvvB, rb0, rb1)
            const float k0 = (ra0 + sa0) + (rb0 + __shfl_xor(rb0, 8));
            const float k1 = (ra1 + sa1) + (rb1 + __shfl_xor(rb1, 8));
            // RK4 stage update in registers (uniform scalar branches on s)
            float zs0, zs1;
            if (s == 3) {
                z32r[0] = fmaf(ksumr[0] + k0, 1.f / 6.f, z32r[0]); zs0 = z32r[0];
                z32r[1] = fmaf(ksumr[1] + k1, 1.f / 6.f, z32r[1]); zs1 = z32r[1];
            } else {
                ksumr[0] = (s == 0) ? k0 : fmaf(2.f, k0, ksumr[0]);
                ksumr[1] = (s == 0) ? k1 : fmaf(2.f, k1, ksumr[1]);
                const float alpha = (s == 2) ? 1.f : 0.5f;
                zs0 = fmaf(alpha, k0, z32r[0]);
                zs1 = fmaf(alpha, k1, z32r[1]);
            }
            if (lr < 8) {
                z16[row0 + 0][hh] = (f16)zs0;
                z16[row0 + 1][hh] = (f16)zs1;
            }
            __syncthreads();
        }
    }

    // ---- epilogue: out = zT @ W_out^T + b_out ----
    if (lr < 8) {
        zf[row0 + 0][hh] = z32r[0];
        zf[row0 + 1][hh] = z32r[1];
    }
    __syncthreads();
    if (tid < 64) {
        const int b = lane >> 3, j0 = lane & 7;
        float p = 0.f;
#pragma unroll
        for (int m = 0; m < 8; ++m) p += zf[b][j0 + 8 * m] * W_out[j0 + 8 * m];
        p += __shfl_xor(p, 1, 64);
        p += __shfl_xor(p, 2, 64);
        p += __shfl_xor(p, 4, 64);
        if (j0 == 0) out[blk * BB + b] = p + b_out[0];
    }
}

extern "C" void kernel_launch(void* const* d_in, const int* in_sizes, int n_in,
                              void* d_out, int out_size, void* d_ws, size_t ws_size,
                              hipStream_t stream) {
    const float* coeffs = (const float*)d_in[0];
    const float* W_init = (const float*)d_in[1];
    const float* b_init = (const float*)d_in[2];
    const float* W1     = (const float*)d_in[3];
    const float* b1     = (const float*)d_in[4];
    const float* W2     = (const float*)d_in[5];
    const float* b2     = (const float*)d_in[6];
    const float* W_out  = (const float*)d_in[7];
    const float* b_out  = (const float*)d_in[8];
    cde_kernel<<<256, 512, 0, stream>>>(coeffs, W_init, b_init, W1, b1, W2, b2,
                                        W_out, b_out, (float*)d_out);
}

// Round 18
// 662.199 us; speedup vs baseline: 1.1719x; 1.0476x over previous
//
#include <hip/hip_runtime.h>

#define L_DIM 128
#define BB 8          // real batch rows per block (padded to 16 for MFMA)

typedef _Float16 f16;
typedef _Float16 f16x8 __attribute__((ext_vector_type(8)));
typedef float f32x4 __attribute__((ext_vector_type(4)));

// tanh(u + b) with bias pre-scaled into the exp2 argument: bk = 2*log2(e)*b.
__device__ __forceinline__ float fast_tanh_b(float x, float bk) {
    float e = __builtin_amdgcn_exp2f(fmaf(x, 2.8853900817779268f, bk));
    float r = __builtin_amdgcn_rcpf(e + 1.0f);
    return fmaf(-2.0f, r, 1.0f);   // large +x -> 1; large -x -> -1
}

// waves_per_eu(2): unified budget 256 regs/wave (128 arch + 128 AGPR w2f).
// Proven best regime (r5 = 703us; r2/r8/r9 occupancy pushes all spill-regressed).
__attribute__((amdgpu_flat_work_group_size(512, 512), amdgpu_waves_per_eu(2)))
__global__ void
cde_kernel(const float* __restrict__ coeffs,
           const float* __restrict__ W_init, const float* __restrict__ b_init,
           const float* __restrict__ W1, const float* __restrict__ b1,
           const float* __restrict__ W2, const float* __restrict__ b2,
           const float* __restrict__ W_out, const float* __restrict__ b_out,
           float* __restrict__ out)
{
    __shared__ __align__(16) f16   z16[16][72];        // fp16 z (rows 8-15 = 0, static)
    __shared__ __align__(16) f16   h16[16][136];       // fp16 hidden activations
    __shared__ __align__(16) float dxT[2][3][16][20];  // [buf][which][c][b]
    __shared__ __align__(16) float zf[BB][64];         // epilogue gather

    const int tid  = threadIdx.x;
    const int blk  = blockIdx.x;
    const int lane = tid & 63;
    const int w    = tid >> 6;        // wave 0..7
    const int q    = lane >> 4;       // quarter-wave 0..3
    const int lr   = lane & 15;
    // GEMM2 column permutation: col lr of tile tau -> outc = hh*16 + c with
    //   hh = w*8 + (lr&7)  (lane-invariant over tau),  c = 2*tau + (lr>>3)
    // => c-sum = register accumulate over tau + ONE shfl_xor(8).
    const int hh   = w * 8 + (lr & 7);
    const int chp  = lr >> 3;
    // After lane-compression this lane owns rows row0, row0+1 (all real):
    const int row0 = (q & 1) * 4 + (q >> 1) * 2;   // q: 0->0, 1->4, 2->2, 3->6

    // ---- one-time: weight fragments into registers ----
    f16x8 w2f[8][4];
    float b2k[8];
#pragma unroll
    for (int t8 = 0; t8 < 8; ++t8) {
        const int outc = hh * 16 + 2 * t8 + chp;
        b2k[t8] = 2.8853900817779268f * b2[outc];
#pragma unroll
        for (int kc = 0; kc < 4; ++kc) {
            const float* src = W2 + (size_t)outc * 128 + kc * 32 + q * 8;
            f16x8 v;
#pragma unroll
            for (int i = 0; i < 8; ++i) v[i] = (f16)src[i];
            w2f[t8][kc] = v;
        }
    }
    f16x8 w1f[2];
#pragma unroll
    for (int kc = 0; kc < 2; ++kc) {
        const float* src = W1 + (size_t)(w * 16 + lr) * 64 + kc * 32 + q * 8;
        f16x8 v;
#pragma unroll
        for (int i = 0; i < 8; ++i) v[i] = (f16)src[i];
        w1f[kc] = v;
    }
    const float b1r = b1[w * 16 + lr];
    const f32x4 zero4 = {0.f, 0.f, 0.f, 0.f};   // persistent C-init quad

    // ---- init: z0 = X0 @ W_init^T + b_init for (b = row0+j, hh) ----
    float z32r[2], ksumr[2];
#pragma unroll
    for (int j = 0; j < 2; ++j) {
        const float* x0 = coeffs + (size_t)(blk * BB + row0 + j) * (L_DIM - 1) * 64;
        float a = b_init[hh];
#pragma unroll
        for (int c = 0; c < 16; ++c) a = fmaf(x0[c], W_init[hh * 16 + c], a);
        z32r[j] = a;
        ksumr[j] = 0.f;
        if (lr < 8) z16[row0 + j][hh] = (f16)a;   // lr<8 <=> chp==0; hh=w*8+lr
    }
    for (int i = tid; i < 8 * 72; i += 512) z16[8 + i / 72][i % 72] = (f16)0.f;  // pad rows
    if (tid < BB * 16) {   // spline derivs for step 0 -> buffer 0
        const int b = tid >> 4, c = tid & 15;
        const float* seg = coeffs + (size_t)(blk * BB + b) * (L_DIM - 1) * 64;
        float bv = seg[16 + c], cv = seg[32 + c], dv = seg[48 + c];
        dxT[0][0][c][b] = bv;
        dxT[0][1][c][b] = fmaf(0.25f, dv, fmaf(0.5f, cv, bv));
        dxT[0][2][c][b] = seg[64 + 16 + c];
    }
    __syncthreads();

    // 4-MFMA chain for one tile, C starting from the persistent zero quad
#define G2TILE(dst, T) \
    f32x4 dst = __builtin_amdgcn_mfma_f32_16x16x32_f16(af0, w2f[T][0], zero4, 0, 0, 0); \
    dst = __builtin_amdgcn_mfma_f32_16x16x32_f16(af1, w2f[T][1], dst, 0, 0, 0);         \
    dst = __builtin_amdgcn_mfma_f32_16x16x32_f16(af2, w2f[T][2], dst, 0, 0, 0);         \
    dst = __builtin_amdgcn_mfma_f32_16x16x32_f16(af3, w2f[T][3], dst, 0, 0, 0);

    // tail for one finished tile: compress (rows 0-7 real) -> tanh -> dX-fma
#define G2TAIL(src, T) {                                                  \
    float u0 = __shfl_xor(src[2], 32);                                    \
    float u1 = __shfl_xor(src[3], 32);                                    \
    float g0 = fast_tanh_b((lane < 32) ? src[0] : u0, b2k[T]);            \
    float g1 = fast_tanh_b((lane < 32) ? src[1] : u1, b2k[T]);            \
    ka0 = fmaf(g0, dvv[(T) & 3].x, ka0);                                  \
    ka1 = fmaf(g1, dvv[(T) & 3].y, ka1); }

    // ---- main loop: 127 RK4 steps x 4 f-evals, 2 barriers per f-eval ----
    for (int t = 0; t < L_DIM - 1; ++t) {
        const int buf = t & 1;
        float pb = 0.f, pc = 0.f, pd = 0.f, pe = 0.f;   // dxT prefetch (s2 load, s3 write)
#pragma unroll
        for (int s = 0; s < 4; ++s) {
            // Phase A: GEMM1  h = relu(z @ W1^T + b1)
            {
                f16x8 za0 = *(const f16x8*)&z16[lr][q * 8];
                f16x8 za1 = *(const f16x8*)&z16[lr][32 + q * 8];
                f32x4 hacc = __builtin_amdgcn_mfma_f32_16x16x32_f16(za0, w1f[0], zero4, 0, 0, 0);
                hacc = __builtin_amdgcn_mfma_f32_16x16x32_f16(za1, w1f[1], hacc, 0, 0, 0);
#pragma unroll
                for (int r = 0; r < 4; ++r)
                    h16[q * 4 + r][w * 16 + lr] = (f16)fmaxf(hacc[r] + b1r, 0.f);
            }
            __syncthreads();

            // Phase B: GEMM2, TILE-outer / kc-inner. Each tile's 4-MFMA chain
            // completes independently (scoreboard), so tile T's tail overlaps
            // tile T+1's in-flight MFMAs instead of waiting for all 32.
            const int ds = (s + 1) >> 1;            // 0,1,1,2
            float ka0 = 0.f, ka1 = 0.f;
#pragma unroll
            for (int hf = 0; hf < 2; ++hf) {
                float2 dvv[4];
#pragma unroll
                for (int tt = 0; tt < 4; ++tt)
                    dvv[tt] = *(const float2*)&dxT[buf][ds][2 * (hf * 4 + tt) + chp][row0];
                const f16x8 af0 = *(const f16x8*)&h16[lr][q * 8];
                const f16x8 af1 = *(const f16x8*)&h16[lr][32 + q * 8];
                const f16x8 af2 = *(const f16x8*)&h16[lr][64 + q * 8];
                const f16x8 af3 = *(const f16x8*)&h16[lr][96 + q * 8];
                G2TILE(a0, hf * 4 + 0)
                G2TILE(a1, hf * 4 + 1)
                G2TAIL(a0, hf * 4 + 0)              // overlaps a1's drain
                G2TILE(a2, hf * 4 + 2)
                G2TAIL(a1, hf * 4 + 1)              // overlaps a2's drain
                G2TILE(a3, hf * 4 + 3)
                if (hf == 0 && s == 2 && t < L_DIM - 2 && tid < 128) {  // issue next-step loads
                    const int b = tid >> 4, c = tid & 15;
                    const float* seg = coeffs + ((size_t)(blk * BB + b) * (L_DIM - 1) + (t + 1)) * 64;
                    pb = seg[16 + c]; pc = seg[32 + c]; pd = seg[48 + c];
                    pe = (t + 1 < L_DIM - 2) ? seg[80 + c] : 0.f;
                }
                G2TAIL(a2, hf * 4 + 2)              // overlaps a3's drain
                G2TAIL(a3, hf * 4 + 3)
            }
            // complete the c-sum: one shuffle (partner lane lr^8 has other parity)
            ka0 += __shfl_xor(ka0, 8);
            ka1 += __shfl_xor(ka1, 8);
            // RK4 stage update in registers (uniform scalar branches on s)
            float zs0, zs1;
            if (s == 3) {
                z32r[0] = fmaf(ksumr[0] + ka0, 1.f / 6.f, z32r[0]); zs0 = z32r[0];
                z32r[1] = fmaf(ksumr[1] + ka1, 1.f / 6.f, z32r[1]); zs1 = z32r[1];
            } else {
                ksumr[0] = (s == 0) ? ka0 : fmaf(2.f, ka0, ksumr[0]);
                ksumr[1] = (s == 0) ? ka1 : fmaf(2.f, ka1, ksumr[1]);
                const float alpha = (s == 2) ? 1.f : 0.5f;
                zs0 = fmaf(alpha, ka0, z32r[0]);
                zs1 = fmaf(alpha, ka1, z32r[1]);
            }
            if (lr < 8) {
                z16[row0 + 0][hh] = (f16)zs0;
                z16[row0 + 1][hh] = (f16)zs1;
            }
            if (s == 3 && t < L_DIM - 2 && tid < 128) {   // write next-step spline derivs
                const int b = tid >> 4, c = tid & 15;
                dxT[buf ^ 1][0][c][b] = pb;
                dxT[buf ^ 1][1][c][b] = fmaf(0.25f, pd, fmaf(0.5f, pc, pb));
                dxT[buf ^ 1][2][c][b] = (t + 1 < L_DIM - 2) ? pe : (pb + pc + pd);
            }
            __syncthreads();
        }
    }

    // ---- epilogue: out = zT @ W_out^T + b_out ----
    if (lr < 8) {
        zf[row0 + 0][hh] = z32r[0];
        zf[row0 + 1][hh] = z32r[1];
    }
    __syncthreads();
    if (tid < 64) {
        const int b = lane >> 3, j0 = lane & 7;
        float p = 0.f;
#pragma unroll
        for (int m = 0; m < 8; ++m) p += zf[b][j0 + 8 * m] * W_out[j0 + 8 * m];
        p += __shfl_xor(p, 1, 64);
        p += __shfl_xor(p, 2, 64);
        p += __shfl_xor(p, 4, 64);
        if (j0 == 0) out[blk * BB + b] = p + b_out[0];
    }
}

extern "C" void kernel_launch(void* const* d_in, const int* in_sizes, int n_in,
                              void* d_out, int out_size, void* d_ws, size_t ws_size,
                              hipStream_t stream) {
    const float* coeffs = (const float*)d_in[0];
    const float* W_init = (const float*)d_in[1];
    const float* b_init = (const float*)d_in[2];
    const float* W1     = (const float*)d_in[3];
    const float* b1     = (const float*)d_in[4];
    const float* W2     = (const float*)d_in[5];
    const float* b2     = (const float*)d_in[6];
    const float* W_out  = (const float*)d_in[7];
    const float* b_out  = (const float*)d_in[8];
    cde_kernel<<<256, 512, 0, stream>>>(coeffs, W_init, b_init, W1, b1, W2, b2,
                                        W_out, b_out, (float*)d_out);
}